// Round 7
// baseline (371.650 us; speedup 1.0000x reference)
//
#include <hip/hip_runtime.h>
#include <hip/hip_bf16.h>

// ---------------------------------------------------------------------------
// 3-layer GCN. CSR build: privatized bucket scatter + LDS-ordered fill.
// All 128-wide node matrices stored feature-BLOCKED [8][Npad][16] bf16 so the
// gather can be XCD-sliced: block (blockIdx&7)==s touches only slice s
// (3.2 MB, L2-resident per XCD). MFMA GEMM reads/writes blocked natively.
// ---------------------------------------------------------------------------

#define PBUCK  800          // max buckets (n_nodes/128 rounded up, padded)
#define CAPB   4096         // records per bucket region (mean 2046, ~45 sigma)

typedef __attribute__((ext_vector_type(8))) short short8;
typedef __attribute__((ext_vector_type(4))) float f32x4;

__device__ __forceinline__ float bflo(unsigned u) { return __uint_as_float(u << 16); }
__device__ __forceinline__ float bfhi(unsigned u) { return __uint_as_float(u & 0xffff0000u); }
__device__ __forceinline__ unsigned short f2bf(float f) {
    unsigned u = __float_as_uint(f);
    u = (u + 0x7fffu + ((u >> 16) & 1u)) >> 16;
    return (unsigned short)u;
}
__device__ __forceinline__ unsigned packbf(float a, float b) {
    return (unsigned)f2bf(a) | ((unsigned)f2bf(b) << 16);
}
__device__ __forceinline__ short8 as_short8(uint4 v) {
    union { uint4 u; short8 s; } x; x.u = v; return x.s;
}

// ---- fp32 [N,128] -> blocked bf16 [8][Npad][16] ----
__global__ __launch_bounds__(256) void cast_bf16_blk(
    const float* __restrict__ in, unsigned short* __restrict__ out,
    int n_nodes, int n_pad)
{
    int i = blockIdx.x * 256 + threadIdx.x;          // i over n_nodes*16
    if (i >= n_nodes * 16) return;
    int n = i >> 4, q = i & 15;                      // feats [q*8, q*8+8)
    int fb = q >> 1, half = q & 1;
    const float4* p = (const float4*)(in + (size_t)n * 128 + q * 8);
    float4 a = p[0], b = p[1];
    uint4 v = make_uint4(packbf(a.x, a.y), packbf(a.z, a.w),
                         packbf(b.x, b.y), packbf(b.z, b.w));
    *(uint4*)(out + ((size_t)fb * n_pad + n) * 16 + half * 8) = v;
}

// ---- pack W [128x128] fp32 into MFMA B-fragment order (bf16) ----
__global__ __launch_bounds__(256) void pack_w(
    const float* __restrict__ W, unsigned short* __restrict__ Wp)
{
    int t = blockIdx.x * 256 + threadIdx.x;
    if (t >= 2048) return;
    int lane = t & 63, cf = (t >> 6) & 7, ks = t >> 9;
    int c = cf * 16 + (lane & 15);
    int kb = ks * 32 + (lane >> 4) * 8;
    unsigned short e[8];
    #pragma unroll
    for (int j = 0; j < 8; ++j) e[j] = f2bf(W[(size_t)(kb + j) * 128 + c]);
    uint4 v = make_uint4((unsigned)e[0] | ((unsigned)e[1] << 16),
                         (unsigned)e[2] | ((unsigned)e[3] << 16),
                         (unsigned)e[4] | ((unsigned)e[5] << 16),
                         (unsigned)e[6] | ((unsigned)e[7] << 16));
    *(uint4*)(Wp + (size_t)t * 8) = v;
}

// ---- init per-bucket cursors to region bases ----
__global__ __launch_bounds__(256) void init_pcur(int* __restrict__ pcur)
{
    int i = blockIdx.x * 256 + threadIdx.x;
    if (i < PBUCK) pcur[i] = i * CAPB;
}

// ---- privatized scatter: LDS hist -> one fetch-add per (block,bucket) ----
__global__ __launch_bounds__(1024) void scatter_priv(
    const int* __restrict__ src, const int* __restrict__ dst,
    int* __restrict__ pcur, unsigned* __restrict__ rec, int n_edges)
{
    __shared__ int hist[PBUCK];
    __shared__ int base[PBUCK];
    int nb = gridDim.x;
    int chunk = (n_edges + nb - 1) / nb;
    int lo = blockIdx.x * chunk, hi = min(n_edges, lo + chunk);
    for (int i = threadIdx.x; i < PBUCK; i += 1024) hist[i] = 0;
    __syncthreads();
    for (int e = lo + threadIdx.x; e < hi; e += 1024)
        atomicAdd(&hist[dst[e] >> 7], 1);
    __syncthreads();
    for (int i = threadIdx.x; i < PBUCK; i += 1024) {
        int h = hist[i];
        base[i] = h ? atomicAdd(&pcur[i], h) : 0;
        hist[i] = 0;                    // reuse as local cursor
    }
    __syncthreads();
    for (int e = lo + threadIdx.x; e < hi; e += 1024) {
        int d = dst[e];
        int b = d >> 7;
        int pos = base[b] + atomicAdd(&hist[b], 1);
        if (pos < (b + 1) * CAPB)
            rec[pos] = (unsigned)src[e] | ((unsigned)(d & 127) << 17);
    }
}

// ---- single-block scan of per-bucket totals -> bbase[0..n_buckets] ----
__global__ __launch_bounds__(1024) void bucket_scan(
    const int* __restrict__ pcur, int* __restrict__ bbase,
    int n_buckets, int* __restrict__ offs, int n_nodes)
{
    __shared__ int wsum[16];
    __shared__ int woff[16];
    int tid = threadIdx.x;
    int t = (tid < n_buckets) ? (pcur[tid] - tid * CAPB) : 0;
    int lane = tid & 63, wid = tid >> 6;
    int incl = t;
    #pragma unroll
    for (int off = 1; off < 64; off <<= 1) { int q = __shfl_up(incl, off); if (lane >= off) incl += q; }
    if (lane == 63) wsum[wid] = incl;
    __syncthreads();
    if (wid == 0) {
        int v = (lane < 16) ? wsum[lane] : 0;
        int ii = v;
        #pragma unroll
        for (int off = 1; off < 16; off <<= 1) { int q = __shfl_up(ii, off); if (lane >= off) ii += q; }
        if (lane < 16) woff[lane] = ii - v;
    }
    __syncthreads();
    int excl = woff[wid] + incl - t;
    if (tid <= n_buckets) bbase[tid] = excl;
    if (tid == n_buckets) offs[n_nodes] = excl;
}

// ---- per-bucket: count per node, LDS scan, write offs + ordered esrc ----
__global__ __launch_bounds__(256) void fill_local2(
    const unsigned* __restrict__ rec, const int* __restrict__ pcur,
    const int* __restrict__ bbase, int* __restrict__ offs,
    int* __restrict__ esrc, int n_nodes)
{
    __shared__ int cnt[128];
    __shared__ int cur[128];
    __shared__ int wsum[4];
    int b = blockIdx.x;
    int node0 = b << 7;
    int nN = min(128, n_nodes - node0);
    int tid = threadIdx.x;
    if (tid < 128) cnt[tid] = 0;
    __syncthreads();
    int cbeg = b * CAPB;
    int cend = min(pcur[b], cbeg + CAPB);
    for (int i = cbeg + tid; i < cend; i += 256)
        atomicAdd(&cnt[rec[i] >> 17], 1);
    __syncthreads();
    int c = (tid < 128) ? cnt[tid] : 0;
    int lane = tid & 63, wid = tid >> 6;
    int incl = c;
    #pragma unroll
    for (int off = 1; off < 64; off <<= 1) { int q = __shfl_up(incl, off); if (lane >= off) incl += q; }
    if (lane == 63) wsum[wid] = incl;
    __syncthreads();
    int wpre = 0;
    for (int w = 0; w < wid; ++w) wpre += wsum[w];
    int excl = wpre + incl - c;
    int base = bbase[b];
    if (tid < nN) { offs[node0 + tid] = base + excl; cur[tid] = excl; }
    __syncthreads();
    for (int i = cbeg + tid; i < cend; i += 256) {
        unsigned r = rec[i];
        int pos = atomicAdd(&cur[r >> 17], 1);
        esrc[base + pos] = (int)(r & 0x1FFFFu);
    }
}

// ---- XCD-sliced gather over blocked bf16 [8][Npad][16] -> blocked bf16 ----
// blockIdx&7 = feature slice (-> XCD under round-robin); 8 lanes/node (4B each)
__global__ __launch_bounds__(256) void gather128b(
    const unsigned short* __restrict__ Zb, const int* __restrict__ offs,
    const int* __restrict__ esrc, unsigned short* __restrict__ Ob,
    int n_nodes, int n_pad)
{
    int seg  = blockIdx.x & 7;
    int node = (blockIdx.x >> 3) * 32 + (threadIdx.x >> 3);
    int sub  = threadIdx.x & 7;
    if (node >= n_nodes) return;
    const unsigned short* base = Zb + (size_t)seg * n_pad * 16;
    int beg = offs[node], end = offs[node + 1];
    float a0 = 0.f, a1 = 0.f;
    int e = beg;
    for (; e + 1 < end; e += 2) {
        unsigned v0 = *(const unsigned*)(base + (size_t)esrc[e] * 16 + sub * 2);
        unsigned v1 = *(const unsigned*)(base + (size_t)esrc[e + 1] * 16 + sub * 2);
        a0 += bflo(v0) + bflo(v1);
        a1 += bfhi(v0) + bfhi(v1);
    }
    if (e < end) {
        unsigned v0 = *(const unsigned*)(base + (size_t)esrc[e] * 16 + sub * 2);
        a0 += bflo(v0); a1 += bfhi(v0);
    }
    *(unsigned*)(Ob + ((size_t)seg * n_pad + node) * 16 + sub * 2) = packbf(a0, a1);
}

// ---- gather 40-wide bf16 rows + bias, fp32 out. 16 lanes/node (10 active). ----
__global__ __launch_bounds__(256) void gather40(
    const unsigned short* __restrict__ t, const int* __restrict__ offs,
    const int* __restrict__ esrc, const float* __restrict__ b3,
    float* __restrict__ out, int n_nodes)
{
    int node = blockIdx.x * 16 + (threadIdx.x >> 4);
    int lane = threadIdx.x & 15;
    if (node >= n_nodes || lane >= 10) return;
    float4 bv = *(const float4*)(b3 + lane * 4);
    float a0 = bv.x, a1 = bv.y, a2 = bv.z, a3 = bv.w;
    int beg = offs[node], end = offs[node + 1];
    int e = beg;
    for (; e + 1 < end; e += 2) {
        int s0 = esrc[e], s1 = esrc[e + 1];
        uint2 v0 = *(const uint2*)(t + (size_t)s0 * 40 + lane * 4);
        uint2 v1 = *(const uint2*)(t + (size_t)s1 * 40 + lane * 4);
        a0 += bflo(v0.x) + bflo(v1.x); a1 += bfhi(v0.x) + bfhi(v1.x);
        a2 += bflo(v0.y) + bflo(v1.y); a3 += bfhi(v0.y) + bfhi(v1.y);
    }
    if (e < end) {
        int s0 = esrc[e];
        uint2 v0 = *(const uint2*)(t + (size_t)s0 * 40 + lane * 4);
        a0 += bflo(v0.x); a1 += bfhi(v0.x);
        a2 += bflo(v0.y); a3 += bfhi(v0.y);
    }
    *(float4*)(out + (size_t)node * 40 + lane * 4) = make_float4(a0, a1, a2, a3);
}

// ---- h_out = relu(A @ W + b) via MFMA 16x16x32; A,out blocked [8][Npad][16] ----
__global__ __launch_bounds__(256) void gemm_mfma_128(
    const unsigned short* __restrict__ A, const unsigned short* __restrict__ Wp,
    const float* __restrict__ bias, unsigned short* __restrict__ out,
    int n_rows, int n_pad)
{
    const int tid = threadIdx.x;
    const int w = tid >> 6, l = tid & 63;
    const int row0 = blockIdx.x * 64 + w * 16;
    const int row  = row0 + (l & 15);
    const int q    = l >> 4;

    // a[ks] elems j: A_linear[row][ks*32 + q*8 + j]
    //   -> block fb = ks*2 + (q>>1), offset (q&1)*8
    short8 a[4];
    #pragma unroll
    for (int ks = 0; ks < 4; ++ks) {
        int fb = ks * 2 + (q >> 1);
        a[ks] = as_short8(*(const uint4*)(
            A + ((size_t)fb * n_pad + row) * 16 + (q & 1) * 8));
    }

    #pragma unroll
    for (int cf = 0; cf < 8; ++cf) {
        int col = cf * 16 + (l & 15);
        float bb = bias[col];
        f32x4 acc = { bb, bb, bb, bb };
        #pragma unroll
        for (int ks = 0; ks < 4; ++ks) {
            short8 b = as_short8(*(const uint4*)(Wp + (size_t)((ks * 8 + cf) * 64 + l) * 8));
            acc = __builtin_amdgcn_mfma_f32_16x16x32_bf16(a[ks], b, acc, 0, 0, 0);
        }
        #pragma unroll
        for (int r = 0; r < 4; ++r) {
            int orow = row0 + q * 4 + r;
            if (orow < n_rows)
                out[((size_t)cf * n_pad + orow) * 16 + (l & 15)] = f2bf(fmaxf(acc[r], 0.f));
        }
    }
}

// ---- t = A@W3, A blocked bf16 [8][Npad][16], W3 fp32 [128,40], out bf16 [n,40] ----
__global__ __launch_bounds__(256) void gemm40(
    const unsigned short* __restrict__ A, const float* __restrict__ W,
    unsigned short* __restrict__ out, int n_rows, int n_pad)
{
    __shared__ float Wl[128 * 40];
    __shared__ float Alt[32 * 260];
    const int tid = threadIdx.x;
    const int row0 = blockIdx.x * 256;

    #pragma unroll
    for (int j = 0; j < 5; ++j) {
        int idx = tid + j * 256;
        ((float4*)Wl)[idx] = ((const float4*)W)[idx];
    }

    float4 acc[10];
    #pragma unroll
    for (int c = 0; c < 10; ++c) acc[c] = make_float4(0.f, 0.f, 0.f, 0.f);

    const int grow = row0 + tid;
    for (int kc = 0; kc < 4; ++kc) {
        __syncthreads();
        #pragma unroll
        for (int j = 0; j < 4; ++j) {
            int idx = tid + j * 256;
            int r = idx >> 2, c4 = idx & 3;          // k-range [kc*32+c4*8, +8)
            int gr = row0 + r;
            int fb = kc * 2 + (c4 >> 1);
            uint4 v = make_uint4(0, 0, 0, 0);
            if (gr < n_rows)
                v = *(const uint4*)(A + ((size_t)fb * n_pad + gr) * 16 + (c4 & 1) * 8);
            Alt[(c4 * 8 + 0) * 260 + r] = bflo(v.x);
            Alt[(c4 * 8 + 1) * 260 + r] = bfhi(v.x);
            Alt[(c4 * 8 + 2) * 260 + r] = bflo(v.y);
            Alt[(c4 * 8 + 3) * 260 + r] = bfhi(v.y);
            Alt[(c4 * 8 + 4) * 260 + r] = bflo(v.z);
            Alt[(c4 * 8 + 5) * 260 + r] = bfhi(v.z);
            Alt[(c4 * 8 + 6) * 260 + r] = bflo(v.w);
            Alt[(c4 * 8 + 7) * 260 + r] = bfhi(v.w);
        }
        __syncthreads();
        #pragma unroll
        for (int k = 0; k < 32; ++k) {
            float a = Alt[k * 260 + tid];
            const float4* wr = (const float4*)(Wl + (kc * 32 + k) * 40);
            #pragma unroll
            for (int c = 0; c < 10; ++c) {
                float4 w = wr[c];
                acc[c].x += a * w.x;
                acc[c].y += a * w.y;
                acc[c].z += a * w.z;
                acc[c].w += a * w.w;
            }
        }
    }
    if (grow < n_rows) {
        #pragma unroll
        for (int c = 0; c < 10; ++c) {
            uint2 pv = make_uint2(packbf(acc[c].x, acc[c].y), packbf(acc[c].z, acc[c].w));
            *(uint2*)(out + (size_t)grow * 40 + c * 4) = pv;
        }
    }
}

extern "C" void kernel_launch(void* const* d_in, const int* in_sizes, int n_in,
                              void* d_out, int out_size, void* d_ws, size_t ws_size,
                              hipStream_t stream)
{
    const float* feat = (const float*)d_in[0];
    const int*   src  = (const int*)d_in[1];
    const int*   dst  = (const int*)d_in[2];
    const float* W1   = (const float*)d_in[3];
    const float* b1   = (const float*)d_in[4];
    const float* W2   = (const float*)d_in[5];
    const float* b2   = (const float*)d_in[6];
    const float* W3   = (const float*)d_in[7];
    const float* b3   = (const float*)d_in[8];
    float* out = (float*)d_out;

    const int n_edges = in_sizes[1];
    const int n_nodes = in_sizes[0] / 128;
    const int n_buckets = (n_nodes + 127) >> 7;
    const int gemm_grid = (n_nodes + 63) / 64;
    const int n_pad = gemm_grid * 64;

    // workspace layout (blocked bf16 matrices are [8][n_pad][16])
    unsigned short* AG = (unsigned short*)d_ws;                    // blocked agg
    unsigned short* SC = AG + (size_t)n_pad * 128;                 // blocked feat16->h1; later linear t[N,40]
    unsigned short* SD = SC + (size_t)n_pad * 128;                 // blocked h2 (rec overlay during build)
    unsigned* rec = (unsigned*)SD;                                 // [PBUCK*CAPB]
    int*  esrc = (int*)(SD + (size_t)n_pad * 128);                 // [E]
    int*  offs = esrc + n_edges;                                   // [N+1]
    int*  pcur = offs + n_nodes + 1;                               // [PBUCK]
    int*  bbase = pcur + PBUCK;                                    // [n_buckets+1]
    unsigned short* Wp1 = (unsigned short*)(bbase + n_buckets + 1);// [2048*8]
    unsigned short* Wp2 = Wp1 + 2048 * 8;                          // [2048*8]

    // ---- build ----
    init_pcur<<<(PBUCK + 255) / 256, 256, 0, stream>>>(pcur);
    cast_bf16_blk<<<(n_nodes * 16 + 255) / 256, 256, 0, stream>>>(feat, SC, n_nodes, n_pad);
    pack_w<<<8, 256, 0, stream>>>(W1, Wp1);
    pack_w<<<8, 256, 0, stream>>>(W2, Wp2);
    scatter_priv<<<256, 1024, 0, stream>>>(src, dst, pcur, rec, n_edges);
    bucket_scan<<<1, 1024, 0, stream>>>(pcur, bbase, n_buckets, offs, n_nodes);
    fill_local2<<<n_buckets, 256, 0, stream>>>(rec, pcur, bbase, offs, esrc, n_nodes);

    const int gg8 = 8 * ((n_nodes + 31) / 32);     // sliced gather grid
    const int gg  = (n_nodes + 15) / 16;

    // ---- layer 1 ----
    gather128b<<<gg8, 256, 0, stream>>>(SC, offs, esrc, AG, n_nodes, n_pad);
    gemm_mfma_128<<<gemm_grid, 256, 0, stream>>>(AG, Wp1, b1, SC, n_nodes, n_pad);

    // ---- layer 2 ----
    gather128b<<<gg8, 256, 0, stream>>>(SC, offs, esrc, AG, n_nodes, n_pad);
    gemm_mfma_128<<<gemm_grid, 256, 0, stream>>>(AG, Wp2, b2, SD, n_nodes, n_pad);

    // ---- layer 3: t = h2@W3 (reorder), out = gather(t) + b3 ----
    gemm40<<<(n_nodes + 255) / 256, 256, 0, stream>>>(SD, W3, SC, n_nodes, n_pad);
    gather40<<<gg, 256, 0, stream>>>(SC, offs, esrc, b3, out, n_nodes);
}

// Round 8
// 363.269 us; speedup vs baseline: 1.0231x; 1.0231x over previous
//
#include <hip/hip_runtime.h>
#include <hip/hip_bf16.h>

// ---------------------------------------------------------------------------
// 3-layer GCN. CSR build: privatized bucket scatter + LDS-ordered fill.
// All 128-wide node matrices stored feature-BLOCKED [8][Npad][16] bf16 so the
// gather can be XCD-sliced: block (blockIdx&7)==s touches only slice s
// (3.2 MB, cache-resident). Gather uses 2 lanes/node/slice with 16B loads.
// MFMA GEMM reads/writes blocked natively.
// ---------------------------------------------------------------------------

#define PBUCK  800          // max buckets (n_nodes/128 rounded up, padded)
#define CAPB   4096         // records per bucket region (mean 2046, ~45 sigma)

typedef __attribute__((ext_vector_type(8))) short short8;
typedef __attribute__((ext_vector_type(4))) float f32x4;

__device__ __forceinline__ float bflo(unsigned u) { return __uint_as_float(u << 16); }
__device__ __forceinline__ float bfhi(unsigned u) { return __uint_as_float(u & 0xffff0000u); }
__device__ __forceinline__ unsigned short f2bf(float f) {
    unsigned u = __float_as_uint(f);
    u = (u + 0x7fffu + ((u >> 16) & 1u)) >> 16;
    return (unsigned short)u;
}
__device__ __forceinline__ unsigned packbf(float a, float b) {
    return (unsigned)f2bf(a) | ((unsigned)f2bf(b) << 16);
}
__device__ __forceinline__ short8 as_short8(uint4 v) {
    union { uint4 u; short8 s; } x; x.u = v; return x.s;
}

// ---- fp32 [N,128] -> blocked bf16 [8][Npad][16] ----
__global__ __launch_bounds__(256) void cast_bf16_blk(
    const float* __restrict__ in, unsigned short* __restrict__ out,
    int n_nodes, int n_pad)
{
    int i = blockIdx.x * 256 + threadIdx.x;          // i over n_nodes*16
    if (i >= n_nodes * 16) return;
    int n = i >> 4, q = i & 15;                      // feats [q*8, q*8+8)
    int fb = q >> 1, half = q & 1;
    const float4* p = (const float4*)(in + (size_t)n * 128 + q * 8);
    float4 a = p[0], b = p[1];
    uint4 v = make_uint4(packbf(a.x, a.y), packbf(a.z, a.w),
                         packbf(b.x, b.y), packbf(b.z, b.w));
    *(uint4*)(out + ((size_t)fb * n_pad + n) * 16 + half * 8) = v;
}

// ---- pack W [128x128] fp32 into MFMA B-fragment order (bf16) ----
__global__ __launch_bounds__(256) void pack_w(
    const float* __restrict__ W, unsigned short* __restrict__ Wp)
{
    int t = blockIdx.x * 256 + threadIdx.x;
    if (t >= 2048) return;
    int lane = t & 63, cf = (t >> 6) & 7, ks = t >> 9;
    int c = cf * 16 + (lane & 15);
    int kb = ks * 32 + (lane >> 4) * 8;
    unsigned short e[8];
    #pragma unroll
    for (int j = 0; j < 8; ++j) e[j] = f2bf(W[(size_t)(kb + j) * 128 + c]);
    uint4 v = make_uint4((unsigned)e[0] | ((unsigned)e[1] << 16),
                         (unsigned)e[2] | ((unsigned)e[3] << 16),
                         (unsigned)e[4] | ((unsigned)e[5] << 16),
                         (unsigned)e[6] | ((unsigned)e[7] << 16));
    *(uint4*)(Wp + (size_t)t * 8) = v;
}

// ---- init per-bucket cursors to region bases ----
__global__ __launch_bounds__(256) void init_pcur(int* __restrict__ pcur)
{
    int i = blockIdx.x * 256 + threadIdx.x;
    if (i < PBUCK) pcur[i] = i * CAPB;
}

// ---- privatized scatter: LDS hist -> one fetch-add per (block,bucket) ----
__global__ __launch_bounds__(1024) void scatter_priv(
    const int* __restrict__ src, const int* __restrict__ dst,
    int* __restrict__ pcur, unsigned* __restrict__ rec, int n_edges)
{
    __shared__ int hist[PBUCK];
    __shared__ int base[PBUCK];
    int nb = gridDim.x;
    int chunk = (n_edges + nb - 1) / nb;
    int lo = blockIdx.x * chunk, hi = min(n_edges, lo + chunk);
    for (int i = threadIdx.x; i < PBUCK; i += 1024) hist[i] = 0;
    __syncthreads();
    for (int e = lo + threadIdx.x; e < hi; e += 1024)
        atomicAdd(&hist[dst[e] >> 7], 1);
    __syncthreads();
    for (int i = threadIdx.x; i < PBUCK; i += 1024) {
        int h = hist[i];
        base[i] = h ? atomicAdd(&pcur[i], h) : 0;
        hist[i] = 0;                    // reuse as local cursor
    }
    __syncthreads();
    for (int e = lo + threadIdx.x; e < hi; e += 1024) {
        int d = dst[e];
        int b = d >> 7;
        int pos = base[b] + atomicAdd(&hist[b], 1);
        if (pos < (b + 1) * CAPB)
            rec[pos] = (unsigned)src[e] | ((unsigned)(d & 127) << 17);
    }
}

// ---- single-block scan of per-bucket totals -> bbase[0..n_buckets] ----
__global__ __launch_bounds__(1024) void bucket_scan(
    const int* __restrict__ pcur, int* __restrict__ bbase,
    int n_buckets, int* __restrict__ offs, int n_nodes)
{
    __shared__ int wsum[16];
    __shared__ int woff[16];
    int tid = threadIdx.x;
    int t = (tid < n_buckets) ? (pcur[tid] - tid * CAPB) : 0;
    int lane = tid & 63, wid = tid >> 6;
    int incl = t;
    #pragma unroll
    for (int off = 1; off < 64; off <<= 1) { int q = __shfl_up(incl, off); if (lane >= off) incl += q; }
    if (lane == 63) wsum[wid] = incl;
    __syncthreads();
    if (wid == 0) {
        int v = (lane < 16) ? wsum[lane] : 0;
        int ii = v;
        #pragma unroll
        for (int off = 1; off < 16; off <<= 1) { int q = __shfl_up(ii, off); if (lane >= off) ii += q; }
        if (lane < 16) woff[lane] = ii - v;
    }
    __syncthreads();
    int excl = woff[wid] + incl - t;
    if (tid <= n_buckets) bbase[tid] = excl;
    if (tid == n_buckets) offs[n_nodes] = excl;
}

// ---- per-bucket: count per node, LDS scan, write offs + ordered esrc ----
__global__ __launch_bounds__(256) void fill_local2(
    const unsigned* __restrict__ rec, const int* __restrict__ pcur,
    const int* __restrict__ bbase, int* __restrict__ offs,
    int* __restrict__ esrc, int n_nodes)
{
    __shared__ int cnt[128];
    __shared__ int cur[128];
    __shared__ int wsum[4];
    int b = blockIdx.x;
    int node0 = b << 7;
    int nN = min(128, n_nodes - node0);
    int tid = threadIdx.x;
    if (tid < 128) cnt[tid] = 0;
    __syncthreads();
    int cbeg = b * CAPB;
    int cend = min(pcur[b], cbeg + CAPB);
    for (int i = cbeg + tid; i < cend; i += 256)
        atomicAdd(&cnt[rec[i] >> 17], 1);
    __syncthreads();
    int c = (tid < 128) ? cnt[tid] : 0;
    int lane = tid & 63, wid = tid >> 6;
    int incl = c;
    #pragma unroll
    for (int off = 1; off < 64; off <<= 1) { int q = __shfl_up(incl, off); if (lane >= off) incl += q; }
    if (lane == 63) wsum[wid] = incl;
    __syncthreads();
    int wpre = 0;
    for (int w = 0; w < wid; ++w) wpre += wsum[w];
    int excl = wpre + incl - c;
    int base = bbase[b];
    if (tid < nN) { offs[node0 + tid] = base + excl; cur[tid] = excl; }
    __syncthreads();
    for (int i = cbeg + tid; i < cend; i += 256) {
        unsigned r = rec[i];
        int pos = atomicAdd(&cur[r >> 17], 1);
        esrc[base + pos] = (int)(r & 0x1FFFFu);
    }
}

// ---- XCD-sliced gather over blocked bf16 [8][Npad][16] -> blocked bf16 ----
// blockIdx&7 = feature slice; 2 lanes/node/slice, 16B loads; esrc as int2.
__global__ __launch_bounds__(256) void gather128c(
    const unsigned short* __restrict__ Zb, const int* __restrict__ offs,
    const int* __restrict__ esrc, unsigned short* __restrict__ Ob,
    int n_nodes, int n_pad)
{
    int seg  = blockIdx.x & 7;
    int node = (blockIdx.x >> 3) * 128 + (threadIdx.x >> 1);
    int half = threadIdx.x & 1;                     // which 16B half of 32B row
    if (node >= n_nodes) return;
    const unsigned short* base = Zb + (size_t)seg * n_pad * 16 + half * 8;
    int beg = offs[node], end = offs[node + 1];
    float a0 = 0.f, a1 = 0.f, a2 = 0.f, a3 = 0.f;
    float a4 = 0.f, a5 = 0.f, a6 = 0.f, a7 = 0.f;
    int e = beg;
    if (e < end && (e & 1)) {                       // peel to align int2 loads
        uint4 v = *(const uint4*)(base + (size_t)esrc[e] * 16);
        a0 += bflo(v.x); a1 += bfhi(v.x); a2 += bflo(v.y); a3 += bfhi(v.y);
        a4 += bflo(v.z); a5 += bfhi(v.z); a6 += bflo(v.w); a7 += bfhi(v.w);
        ++e;
    }
    for (; e + 1 < end; e += 2) {
        int2 ss = *(const int2*)(esrc + e);
        uint4 v0 = *(const uint4*)(base + (size_t)ss.x * 16);
        uint4 v1 = *(const uint4*)(base + (size_t)ss.y * 16);
        a0 += bflo(v0.x) + bflo(v1.x); a1 += bfhi(v0.x) + bfhi(v1.x);
        a2 += bflo(v0.y) + bflo(v1.y); a3 += bfhi(v0.y) + bfhi(v1.y);
        a4 += bflo(v0.z) + bflo(v1.z); a5 += bfhi(v0.z) + bfhi(v1.z);
        a6 += bflo(v0.w) + bflo(v1.w); a7 += bfhi(v0.w) + bfhi(v1.w);
    }
    if (e < end) {
        uint4 v = *(const uint4*)(base + (size_t)esrc[e] * 16);
        a0 += bflo(v.x); a1 += bfhi(v.x); a2 += bflo(v.y); a3 += bfhi(v.y);
        a4 += bflo(v.z); a5 += bfhi(v.z); a6 += bflo(v.w); a7 += bfhi(v.w);
    }
    uint4 o = make_uint4(packbf(a0, a1), packbf(a2, a3),
                         packbf(a4, a5), packbf(a6, a7));
    *(uint4*)(Ob + ((size_t)seg * n_pad + node) * 16 + half * 8) = o;
}

// ---- gather 40-wide bf16 rows + bias, fp32 out. 16 lanes/node (10 active). ----
__global__ __launch_bounds__(256) void gather40(
    const unsigned short* __restrict__ t, const int* __restrict__ offs,
    const int* __restrict__ esrc, const float* __restrict__ b3,
    float* __restrict__ out, int n_nodes)
{
    int node = blockIdx.x * 16 + (threadIdx.x >> 4);
    int lane = threadIdx.x & 15;
    if (node >= n_nodes || lane >= 10) return;
    float4 bv = *(const float4*)(b3 + lane * 4);
    float a0 = bv.x, a1 = bv.y, a2 = bv.z, a3 = bv.w;
    int beg = offs[node], end = offs[node + 1];
    int e = beg;
    for (; e + 1 < end; e += 2) {
        int s0 = esrc[e], s1 = esrc[e + 1];
        uint2 v0 = *(const uint2*)(t + (size_t)s0 * 40 + lane * 4);
        uint2 v1 = *(const uint2*)(t + (size_t)s1 * 40 + lane * 4);
        a0 += bflo(v0.x) + bflo(v1.x); a1 += bfhi(v0.x) + bfhi(v1.x);
        a2 += bflo(v0.y) + bflo(v1.y); a3 += bfhi(v0.y) + bfhi(v1.y);
    }
    if (e < end) {
        int s0 = esrc[e];
        uint2 v0 = *(const uint2*)(t + (size_t)s0 * 40 + lane * 4);
        a0 += bflo(v0.x); a1 += bfhi(v0.x);
        a2 += bflo(v0.y); a3 += bfhi(v0.y);
    }
    *(float4*)(out + (size_t)node * 40 + lane * 4) = make_float4(a0, a1, a2, a3);
}

// ---- h_out = relu(A @ W + b) via MFMA 16x16x32; A,out blocked [8][Npad][16] ----
__global__ __launch_bounds__(256) void gemm_mfma_128(
    const unsigned short* __restrict__ A, const unsigned short* __restrict__ Wp,
    const float* __restrict__ bias, unsigned short* __restrict__ out,
    int n_rows, int n_pad)
{
    const int tid = threadIdx.x;
    const int w = tid >> 6, l = tid & 63;
    const int row0 = blockIdx.x * 64 + w * 16;
    const int row  = row0 + (l & 15);
    const int q    = l >> 4;

    short8 a[4];
    #pragma unroll
    for (int ks = 0; ks < 4; ++ks) {
        int fb = ks * 2 + (q >> 1);
        a[ks] = as_short8(*(const uint4*)(
            A + ((size_t)fb * n_pad + row) * 16 + (q & 1) * 8));
    }

    #pragma unroll
    for (int cf = 0; cf < 8; ++cf) {
        int col = cf * 16 + (l & 15);
        float bb = bias[col];
        f32x4 acc = { bb, bb, bb, bb };
        #pragma unroll
        for (int ks = 0; ks < 4; ++ks) {
            short8 b = as_short8(*(const uint4*)(Wp + (size_t)((ks * 8 + cf) * 64 + l) * 8));
            acc = __builtin_amdgcn_mfma_f32_16x16x32_bf16(a[ks], b, acc, 0, 0, 0);
        }
        #pragma unroll
        for (int r = 0; r < 4; ++r) {
            int orow = row0 + q * 4 + r;
            if (orow < n_rows)
                out[((size_t)cf * n_pad + orow) * 16 + (l & 15)] = f2bf(fmaxf(acc[r], 0.f));
        }
    }
}

// ---- t = A@W3, A blocked bf16 [8][Npad][16], W3 fp32 [128,40], out bf16 [n,40] ----
__global__ __launch_bounds__(256) void gemm40(
    const unsigned short* __restrict__ A, const float* __restrict__ W,
    unsigned short* __restrict__ out, int n_rows, int n_pad)
{
    __shared__ float Wl[128 * 40];
    __shared__ float Alt[32 * 260];
    const int tid = threadIdx.x;
    const int row0 = blockIdx.x * 256;

    #pragma unroll
    for (int j = 0; j < 5; ++j) {
        int idx = tid + j * 256;
        ((float4*)Wl)[idx] = ((const float4*)W)[idx];
    }

    float4 acc[10];
    #pragma unroll
    for (int c = 0; c < 10; ++c) acc[c] = make_float4(0.f, 0.f, 0.f, 0.f);

    const int grow = row0 + tid;
    for (int kc = 0; kc < 4; ++kc) {
        __syncthreads();
        #pragma unroll
        for (int j = 0; j < 4; ++j) {
            int idx = tid + j * 256;
            int r = idx >> 2, c4 = idx & 3;          // k-range [kc*32+c4*8, +8)
            int gr = row0 + r;
            int fb = kc * 2 + (c4 >> 1);
            uint4 v = make_uint4(0, 0, 0, 0);
            if (gr < n_rows)
                v = *(const uint4*)(A + ((size_t)fb * n_pad + gr) * 16 + (c4 & 1) * 8);
            Alt[(c4 * 8 + 0) * 260 + r] = bflo(v.x);
            Alt[(c4 * 8 + 1) * 260 + r] = bfhi(v.x);
            Alt[(c4 * 8 + 2) * 260 + r] = bflo(v.y);
            Alt[(c4 * 8 + 3) * 260 + r] = bfhi(v.y);
            Alt[(c4 * 8 + 4) * 260 + r] = bflo(v.z);
            Alt[(c4 * 8 + 5) * 260 + r] = bfhi(v.z);
            Alt[(c4 * 8 + 6) * 260 + r] = bflo(v.w);
            Alt[(c4 * 8 + 7) * 260 + r] = bfhi(v.w);
        }
        __syncthreads();
        #pragma unroll
        for (int k = 0; k < 32; ++k) {
            float a = Alt[k * 260 + tid];
            const float4* wr = (const float4*)(Wl + (kc * 32 + k) * 40);
            #pragma unroll
            for (int c = 0; c < 10; ++c) {
                float4 w = wr[c];
                acc[c].x += a * w.x;
                acc[c].y += a * w.y;
                acc[c].z += a * w.z;
                acc[c].w += a * w.w;
            }
        }
    }
    if (grow < n_rows) {
        #pragma unroll
        for (int c = 0; c < 10; ++c) {
            uint2 pv = make_uint2(packbf(acc[c].x, acc[c].y), packbf(acc[c].z, acc[c].w));
            *(uint2*)(out + (size_t)grow * 40 + c * 4) = pv;
        }
    }
}

extern "C" void kernel_launch(void* const* d_in, const int* in_sizes, int n_in,
                              void* d_out, int out_size, void* d_ws, size_t ws_size,
                              hipStream_t stream)
{
    const float* feat = (const float*)d_in[0];
    const int*   src  = (const int*)d_in[1];
    const int*   dst  = (const int*)d_in[2];
    const float* W1   = (const float*)d_in[3];
    const float* b1   = (const float*)d_in[4];
    const float* W2   = (const float*)d_in[5];
    const float* b2   = (const float*)d_in[6];
    const float* W3   = (const float*)d_in[7];
    const float* b3   = (const float*)d_in[8];
    float* out = (float*)d_out;

    const int n_edges = in_sizes[1];
    const int n_nodes = in_sizes[0] / 128;
    const int n_buckets = (n_nodes + 127) >> 7;
    const int gemm_grid = (n_nodes + 63) / 64;
    const int n_pad = gemm_grid * 64;

    // workspace layout (blocked bf16 matrices are [8][n_pad][16])
    unsigned short* AG = (unsigned short*)d_ws;                    // blocked agg
    unsigned short* SC = AG + (size_t)n_pad * 128;                 // blocked feat16->h1; later linear t[N,40]
    unsigned short* SD = SC + (size_t)n_pad * 128;                 // blocked h2 (rec overlay during build)
    unsigned* rec = (unsigned*)SD;                                 // [PBUCK*CAPB]
    int*  esrc = (int*)(SD + (size_t)n_pad * 128);                 // [E]
    int*  offs = esrc + n_edges;                                   // [N+1]
    int*  pcur = offs + n_nodes + 1;                               // [PBUCK]
    int*  bbase = pcur + PBUCK;                                    // [n_buckets+1]
    unsigned short* Wp1 = (unsigned short*)(bbase + n_buckets + 1);// [2048*8]
    unsigned short* Wp2 = Wp1 + 2048 * 8;                          // [2048*8]

    // ---- build ----
    init_pcur<<<(PBUCK + 255) / 256, 256, 0, stream>>>(pcur);
    cast_bf16_blk<<<(n_nodes * 16 + 255) / 256, 256, 0, stream>>>(feat, SC, n_nodes, n_pad);
    pack_w<<<8, 256, 0, stream>>>(W1, Wp1);
    pack_w<<<8, 256, 0, stream>>>(W2, Wp2);
    scatter_priv<<<256, 1024, 0, stream>>>(src, dst, pcur, rec, n_edges);
    bucket_scan<<<1, 1024, 0, stream>>>(pcur, bbase, n_buckets, offs, n_nodes);
    fill_local2<<<n_buckets, 256, 0, stream>>>(rec, pcur, bbase, offs, esrc, n_nodes);

    const int gg8 = 8 * ((n_nodes + 127) / 128);   // sliced gather grid
    const int gg  = (n_nodes + 15) / 16;

    // ---- layer 1 ----
    gather128c<<<gg8, 256, 0, stream>>>(SC, offs, esrc, AG, n_nodes, n_pad);
    gemm_mfma_128<<<gemm_grid, 256, 0, stream>>>(AG, Wp1, b1, SC, n_nodes, n_pad);

    // ---- layer 2 ----
    gather128c<<<gg8, 256, 0, stream>>>(SC, offs, esrc, AG, n_nodes, n_pad);
    gemm_mfma_128<<<gemm_grid, 256, 0, stream>>>(AG, Wp2, b2, SD, n_nodes, n_pad);

    // ---- layer 3: t = h2@W3 (reorder), out = gather(t) + b3 ----
    gemm40<<<(n_nodes + 255) / 256, 256, 0, stream>>>(SD, W3, SC, n_nodes, n_pad);
    gather40<<<gg, 256, 0, stream>>>(SC, offs, esrc, b3, out, n_nodes);
}